// Round 18
// baseline (1440.206 us; speedup 1.0000x reference)
//
#include <hip/hip_runtime.h>
#include <hip/hip_bf16.h>

typedef __bf16 bf16;
typedef __bf16 bf16x8 __attribute__((ext_vector_type(8)));
typedef float f32x4 __attribute__((ext_vector_type(4)));

#define B_ 2
#define S_ 1024
#define D_ 1024
#define L_ 8
#define HQ_ 16
#define HK_ 4
#define DH_ 64
#define FF_ 2816
#define V_ 32000

#define OFFD_QKV 0
#define OFFD_WK  1048576
#define OFFD_WV  1310720
#define OFFD_WO  1572864
#define OFFD_W13 2621440
#define OFFD_W2  8388608

#define LGKM0 { asm volatile("s_waitcnt lgkmcnt(0)" ::: "memory"); __builtin_amdgcn_sched_barrier(0); }

// ---------------- mega setup: rope-table + embed/rms + ALL weight transposes ----------------
// segments (blockIdx.x): [0,128) rope | [128,2176) embed+rms | then transpose tiles:
// outw 8000 | wq 2048 | wk 512 | wv 512 | wo 2048 | w1 5632 | w3 5632 | w2 5632 = 32192 total
__global__ __launch_bounds__(256) void setup_k(const int* __restrict__ toks,
                                               const float* __restrict__ emb,
                                               const float* __restrict__ anw0,
                                               float* __restrict__ h,
                                               bf16* __restrict__ xb,
                                               float* __restrict__ tab,
                                               const float* __restrict__ outw,
                                               bf16* __restrict__ outwT,
                                               const float* __restrict__ wq,
                                               const float* __restrict__ wk,
                                               const float* __restrict__ wv,
                                               const float* __restrict__ wo,
                                               const float* __restrict__ w1,
                                               const float* __restrict__ w3,
                                               const float* __restrict__ w2,
                                               bf16* __restrict__ wT,
                                               long long WTS) {
  __shared__ float tile[64][68];
  __shared__ float partial[4];
  int id = blockIdx.x, t = threadIdx.x;

  if (id < 128) {                       // rope table
    int i = id * 256 + t;
    int d = i & 31, s = i >> 5;
    float f = expf(-(2.0f * d / 64.0f) * logf(500000.0f));
    float ang = (float)s * f;
    tab[i * 2]     = cosf(ang);
    tab[i * 2 + 1] = sinf(ang);
    return;
  }
  id -= 128;
  if (id < 2048) {                      // embed + layer-0 rmsnorm
    int row = id;
    int tok = toks[row];
    int base = t * 4;
    f32x4 v = *(const f32x4*)&emb[(size_t)tok * D_ + base];
    *(f32x4*)&h[(size_t)row * D_ + base] = v;
    float ss = v[0]*v[0] + v[1]*v[1] + v[2]*v[2] + v[3]*v[3];
    for (int m = 1; m < 64; m <<= 1) ss += __shfl_xor(ss, m, 64);
    if ((t & 63) == 0) partial[t >> 6] = ss;
    __syncthreads();
    float tot = partial[0] + partial[1] + partial[2] + partial[3];
    float rr = rsqrtf(tot * (1.0f / D_) + 1e-5f);
    f32x4 wv4 = *(const f32x4*)&anw0[base];
    bf16* o = xb + (size_t)row * D_ + base;
    o[0] = (bf16)(v[0] * rr * wv4[0]);
    o[1] = (bf16)(v[1] * rr * wv4[1]);
    o[2] = (bf16)(v[2] * rr * wv4[2]);
    o[3] = (bf16)(v[3] * rr * wv4[3]);
    return;
  }
  id -= 2048;

  const float* src; bf16* dst; int K, N, rowMul, rowAdd, bx, by;
  if (id < 8000) {                      // outw: 1024 x 32000
    src = outw; dst = outwT; K = 1024; N = 32000; rowMul = 1; rowAdd = 0;
    bx = id % 500; by = id / 500;
  } else if ((id -= 8000) < 2048) {     // wq
    int z = id >> 8, r2 = id & 255;
    src = wq + (size_t)z * 1048576; dst = wT + (size_t)z * WTS + OFFD_QKV;
    K = 1024; N = 1024; rowMul = 1; rowAdd = 0; bx = r2 & 15; by = r2 >> 4;
  } else if ((id -= 2048) < 512) {      // wk
    int z = id >> 6, r2 = id & 63;
    src = wk + (size_t)z * 262144; dst = wT + (size_t)z * WTS + OFFD_WK;
    K = 1024; N = 256; rowMul = 1; rowAdd = 0; bx = r2 & 3; by = r2 >> 2;
  } else if ((id -= 512) < 512) {       // wv
    int z = id >> 6, r2 = id & 63;
    src = wv + (size_t)z * 262144; dst = wT + (size_t)z * WTS + OFFD_WV;
    K = 1024; N = 256; rowMul = 1; rowAdd = 0; bx = r2 & 3; by = r2 >> 2;
  } else if ((id -= 512) < 2048) {      // wo
    int z = id >> 8, r2 = id & 255;
    src = wo + (size_t)z * 1048576; dst = wT + (size_t)z * WTS + OFFD_WO;
    K = 1024; N = 1024; rowMul = 1; rowAdd = 0; bx = r2 & 15; by = r2 >> 4;
  } else if ((id -= 2048) < 5632) {     // w1 (interleaved even rows)
    int z = id / 704, r2 = id % 704;
    src = w1 + (size_t)z * 2883584; dst = wT + (size_t)z * WTS + OFFD_W13;
    K = 1024; N = 2816; rowMul = 2; rowAdd = 0; bx = r2 % 44; by = r2 / 44;
  } else if ((id -= 5632) < 5632) {     // w3 (interleaved odd rows)
    int z = id / 704, r2 = id % 704;
    src = w3 + (size_t)z * 2883584; dst = wT + (size_t)z * WTS + OFFD_W13;
    K = 1024; N = 2816; rowMul = 2; rowAdd = 1; bx = r2 % 44; by = r2 / 44;
  } else {                              // w2
    id -= 5632;
    int z = id / 704, r2 = id % 704;
    src = w2 + (size_t)z * 2883584; dst = wT + (size_t)z * WTS + OFFD_W2;
    K = 2816; N = 1024; rowMul = 1; rowAdd = 0; bx = r2 & 15; by = r2 >> 4;
  }

#pragma unroll
  for (int it = 0; it < 4; ++it) {
    int idx = it * 256 + t;
    int r = idx >> 4, c4 = (idx & 15) * 4;
    f32x4 v = *(const f32x4*)&src[(size_t)(by * 64 + r) * N + bx * 64 + c4];
    *(f32x4*)&tile[r][c4] = v;
  }
  __syncthreads();
#pragma unroll
  for (int it = 0; it < 2; ++it) {
    int idx = it * 256 + t;
    int n = idx >> 3, k8 = (idx & 7) * 8;
    bf16x8 o;
#pragma unroll
    for (int j = 0; j < 8; ++j) o[j] = (bf16)tile[k8 + j][n];
    *(bf16x8*)&dst[(size_t)((bx * 64 + n) * rowMul + rowAdd) * K + by * 64 + k8] = o;
  }
}

// ---------------- fallback kernels (!allup path) ----------------
__global__ __launch_bounds__(256) void ropetab_k(float* __restrict__ tab) {
  int i = blockIdx.x * 256 + threadIdx.x;
  if (i >= S_ * 32) return;
  int d = i & 31, s = i >> 5;
  float f = expf(-(2.0f * d / 64.0f) * logf(500000.0f));
  float ang = (float)s * f;
  tab[i * 2]     = cosf(ang);
  tab[i * 2 + 1] = sinf(ang);
}

__global__ __launch_bounds__(256) void embedrms_k(const int* __restrict__ toks,
                                                  const float* __restrict__ emb,
                                                  const float* __restrict__ w,
                                                  float* __restrict__ h,
                                                  bf16* __restrict__ out) {
  int row = blockIdx.x;
  int tok = toks[row];
  int base = threadIdx.x * 4;
  f32x4 v = *(const f32x4*)&emb[(size_t)tok * D_ + base];
  *(f32x4*)&h[(size_t)row * D_ + base] = v;
  float ss = v[0]*v[0] + v[1]*v[1] + v[2]*v[2] + v[3]*v[3];
  for (int m = 1; m < 64; m <<= 1) ss += __shfl_xor(ss, m, 64);
  __shared__ float partial[4];
  if ((threadIdx.x & 63) == 0) partial[threadIdx.x >> 6] = ss;
  __syncthreads();
  float tot = partial[0] + partial[1] + partial[2] + partial[3];
  float rr = rsqrtf(tot * (1.0f / D_) + 1e-5f);
  f32x4 wv = *(const f32x4*)&w[base];
  bf16* o = out + (size_t)row * D_ + base;
  o[0] = (bf16)(v[0] * rr * wv[0]);
  o[1] = (bf16)(v[1] * rr * wv[1]);
  o[2] = (bf16)(v[2] * rr * wv[2]);
  o[3] = (bf16)(v[3] * rr * wv[3]);
}

__global__ __launch_bounds__(256) void transpose_cvt(const float* __restrict__ src,
                                                     bf16* __restrict__ dst,
                                                     int K, int N,
                                                     long long srcStride, long long dstStride,
                                                     int rowMul, int rowAdd) {
  __shared__ float tile[64][68];
  int bx = blockIdx.x, by = blockIdx.y, z = blockIdx.z;
  src += (size_t)z * srcStride;
  dst += (size_t)z * dstStride;
  int t = threadIdx.x;
#pragma unroll
  for (int it = 0; it < 4; ++it) {
    int idx = it * 256 + t;
    int r = idx >> 4, c4 = (idx & 15) * 4;
    f32x4 v = *(const f32x4*)&src[(size_t)(by * 64 + r) * N + bx * 64 + c4];
    *(f32x4*)&tile[r][c4] = v;
  }
  __syncthreads();
#pragma unroll
  for (int it = 0; it < 2; ++it) {
    int idx = it * 256 + t;
    int n = idx >> 3, k8 = (idx & 7) * 8;
    bf16x8 o;
#pragma unroll
    for (int j = 0; j < 8; ++j) o[j] = (bf16)tile[k8 + j][n];
    *(bf16x8*)&dst[(size_t)((bx * 64 + n) * rowMul + rowAdd) * K + by * 64 + k8] = o;
  }
}

// ---------------- rmsnorm: fp32 in -> bf16 out ----------------
__global__ __launch_bounds__(256) void rmsnorm_k(const float* __restrict__ x,
                                                 const float* __restrict__ w,
                                                 bf16* __restrict__ out) {
  int row = blockIdx.x;
  const float* xr = x + (size_t)row * D_;
  int base = threadIdx.x * 4;
  f32x4 v = *(const f32x4*)&xr[base];
  float ss = v[0]*v[0] + v[1]*v[1] + v[2]*v[2] + v[3]*v[3];
  for (int m = 1; m < 64; m <<= 1) ss += __shfl_xor(ss, m, 64);
  __shared__ float partial[4];
  if ((threadIdx.x & 63) == 0) partial[threadIdx.x >> 6] = ss;
  __syncthreads();
  float tot = partial[0] + partial[1] + partial[2] + partial[3];
  float rr = rsqrtf(tot * (1.0f / D_) + 1e-5f);
  f32x4 wv = *(const f32x4*)&w[base];
  bf16* o = out + (size_t)row * D_ + base;
  o[0] = (bf16)(v[0] * rr * wv[0]);
  o[1] = (bf16)(v[1] * rr * wv[1]);
  o[2] = (bf16)(v[2] * rr * wv[2]);
  o[3] = (bf16)(v[3] * rr * wv[3]);
}

// ---------------- fused split-K reduce + residual + rmsnorm ----------------
__global__ __launch_bounds__(256) void redrms_k(const float* __restrict__ p,
                                                float* __restrict__ h,
                                                const float* __restrict__ w,
                                                bf16* __restrict__ out) {
  int row = blockIdx.x;
  int base = threadIdx.x * 4;
  size_t ix = (size_t)row * D_ + base;
  f32x4 a = *(const f32x4*)&p[ix];
  f32x4 bb = *(const f32x4*)&p[ix + 2097152];
  f32x4 v = *(const f32x4*)&h[ix];
  v += a + bb;
  *(f32x4*)&h[ix] = v;
  float ss = v[0]*v[0] + v[1]*v[1] + v[2]*v[2] + v[3]*v[3];
  for (int m = 1; m < 64; m <<= 1) ss += __shfl_xor(ss, m, 64);
  __shared__ float partial[4];
  if ((threadIdx.x & 63) == 0) partial[threadIdx.x >> 6] = ss;
  __syncthreads();
  float tot = partial[0] + partial[1] + partial[2] + partial[3];
  float rr = rsqrtf(tot * (1.0f / D_) + 1e-5f);
  f32x4 wv = *(const f32x4*)&w[base];
  bf16* o = out + (size_t)row * D_ + base;
  o[0] = (bf16)(v[0] * rr * wv[0]);
  o[1] = (bf16)(v[1] * rr * wv[1]);
  o[2] = (bf16)(v[2] * rr * wv[2]);
  o[3] = (bf16)(v[3] * rr * wv[3]);
}

// ---------------- BMx128 2-phase GEMM (wo BM=32; w2 split-K BM=64) ----------------
template <int EPI, int BM>
__global__ __launch_bounds__(256) void gemm_bt(const bf16* __restrict__ A,
                                               const bf16* __restrict__ BT,
                                               void* __restrict__ Cout,
                                               const float* __restrict__ R,
                                               int M, int N, int K,
                                               int lda, int ldb,
                                               int zKoff, long long partStride) {
  constexpr int MR = BM / 32;
  __shared__ bf16 As[BM * 64];
  __shared__ bf16 Bs[128 * 64];
  const int t = threadIdx.x;
  const int w = t >> 6, l = t & 63;
  const int l15 = l & 15, l4 = l >> 4;
  const int bm = blockIdx.x * BM, bn = blockIdx.y * 128;
  const int wr = w >> 1, wc = w & 1;
  const int z = blockIdx.z;

  const bf16* Az = A + (size_t)z * zKoff;
  const bf16* Bz = BT + (size_t)z * zKoff;
  float* Cz = (float*)Cout + (size_t)z * partStride;

  const int srow = t >> 3, scol = (t & 7) * 8;
  const bf16* ag = &Az[(size_t)(bm + srow) * lda + scol];
  const bf16* bg = &Bz[(size_t)(bn + srow) * ldb + scol];
  const int ldsbase = (t & 192) * 8;

  f32x4 acc[MR][4] = {};

  for (int k0 = 0; k0 < K; k0 += 64) {
#pragma unroll
    for (int i = 0; i < BM / 32; ++i)
      __builtin_amdgcn_global_load_lds(
          (const __attribute__((address_space(1))) void*)(ag + (size_t)(i * 32) * lda + k0),
          (__attribute__((address_space(3))) void*)&As[i * 2048 + ldsbase], 16, 0, 0);
#pragma unroll
    for (int i = 0; i < 4; ++i)
      __builtin_amdgcn_global_load_lds(
          (const __attribute__((address_space(1))) void*)(bg + (size_t)(i * 32) * ldb + k0),
          (__attribute__((address_space(3))) void*)&Bs[i * 2048 + ldsbase], 16, 0, 0);
    __syncthreads();
#pragma unroll
    for (int kc = 0; kc < 2; ++kc) {
      bf16x8 af[MR], bfr[4];
#pragma unroll
      for (int m = 0; m < MR; ++m)
        af[m] = *(const bf16x8*)&As[(wr * (BM / 2) + m * 16 + l15) * 64 + kc * 32 + l4 * 8];
#pragma unroll
      for (int n = 0; n < 4; ++n)
        bfr[n] = *(const bf16x8*)&Bs[(wc * 64 + n * 16 + l15) * 64 + kc * 32 + l4 * 8];
#pragma unroll
      for (int m = 0; m < MR; ++m)
#pragma unroll
        for (int n = 0; n < 4; ++n)
          acc[m][n] = __builtin_amdgcn_mfma_f32_16x16x32_bf16(af[m], bfr[n], acc[m][n], 0, 0, 0);
    }
    __syncthreads();
  }

#pragma unroll
  for (int m = 0; m < MR; ++m)
#pragma unroll
    for (int n = 0; n < 4; ++n)
#pragma unroll
      for (int r = 0; r < 4; ++r) {
        int row = bm + wr * (BM / 2) + m * 16 + l4 * 4 + r;
        int col = bn + wc * 64 + n * 16 + l15;
        size_t ix = (size_t)row * N + col;
        float v = acc[m][n][r];
        if (EPI == 0)      Cz[ix] = v;
        else               Cz[ix] = v + R[ix];
      }
}

// ---------------- 256x256 8-phase GEMM, deep-pipeline S2 (logits; 1 tile/block) ----------------
template <int EPI>
__global__ __launch_bounds__(512, 2) void gemm256_bt(const bf16* __restrict__ A,
                                                     const bf16* __restrict__ BT,
                                                     void* __restrict__ Cout,
                                                     const float* __restrict__ R,
                                                     int N, int K) {
  extern __shared__ char smem[];   // 131072 B
  const int t = threadIdx.x;
  const int wid = t >> 6, l = t & 63;
  const int l15 = l & 15, l4 = l >> 4;
  const int wr = wid >> 2, wc = wid & 3;
  const int rsw = (l4 ^ ((l15 >> 1) & 3)) * 16;
  const int csw = ((t & 3) ^ ((t >> 3) & 3)) * 8;

  int nwg = gridDim.x;
  int q = nwg >> 3, r = nwg & 7;
  int xcd = blockIdx.x & 7, jj = blockIdx.x >> 3;
  int L = (xcd < r ? xcd * (q + 1) : r * (q + 1) + (xcd - r) * q) + jj;
  const int bm = (L & 7) * 256, bn = (L >> 3) * 256;

  const int NT = K >> 6;

  auto stage = [&](const bf16* __restrict__ G, int rowbase, int cbase, int buf, int kc, int kt) {
#pragma unroll
    for (int i = 0; i < 2; ++i) {
      int j = i * 512 + t;
      const bf16* src = G + (size_t)(rowbase + (j >> 2)) * K + kt * 64 + kc * 32 + csw;
      __builtin_amdgcn_global_load_lds(
          (const __attribute__((address_space(1))) void*)src,
          (__attribute__((address_space(3))) void*)(smem + cbase + buf * 32768 + kc * 16384 +
                                                    i * 8192 + wid * 1024),
          16, 0, 0);
    }
  };
  auto ldA = [&](int buf, int kc, int m) -> bf16x8 {
    return *(const bf16x8*)(smem + buf * 32768 + kc * 16384 +
                            (wr * 128 + m * 16 + l15) * 64 + rsw);
  };
  auto ldB = [&](int buf, int kc, int n) -> bf16x8 {
    return *(const bf16x8*)(smem + 65536 + buf * 32768 + kc * 16384 +
                            (wc * 64 + n * 16 + l15) * 64 + rsw);
  };

  f32x4 acc[8][4] = {};
  bf16x8 af[4], bq[4];

  auto rd03 = [&](int buf, int kc) {
#pragma unroll
    for (int m = 0; m < 4; ++m) af[m] = ldA(buf, kc, m);
#pragma unroll
    for (int n = 0; n < 4; ++n) bq[n] = ldB(buf, kc, n);
  };
  auto rd47 = [&](int buf, int kc) {
#pragma unroll
    for (int m = 0; m < 4; ++m) af[m] = ldA(buf, kc, 4 + m);
  };
  auto mf_lo = [&]() {
    __builtin_amdgcn_s_setprio(1);
#pragma unroll
    for (int m = 0; m < 4; ++m)
#pragma unroll
      for (int n = 0; n < 4; ++n)
        acc[m][n] = __builtin_amdgcn_mfma_f32_16x16x32_bf16(af[m], bq[n], acc[m][n], 0, 0, 0);
    __builtin_amdgcn_s_setprio(0);
    __builtin_amdgcn_sched_barrier(0);
  };
  auto mf_hi = [&]() {
    __builtin_amdgcn_s_setprio(1);
#pragma unroll
    for (int m = 0; m < 4; ++m)
#pragma unroll
      for (int n = 0; n < 4; ++n)
        acc[4 + m][n] = __builtin_amdgcn_mfma_f32_16x16x32_bf16(af[m], bq[n], acc[4 + m][n], 0, 0, 0);
    __builtin_amdgcn_s_setprio(0);
    __builtin_amdgcn_sched_barrier(0);
  };
#define GBAR { __builtin_amdgcn_sched_barrier(0); __builtin_amdgcn_s_barrier(); }
#define VMW(n) { asm volatile("s_waitcnt vmcnt(" #n ")" ::: "memory"); __builtin_amdgcn_sched_barrier(0); }

  stage(A, bm, 0, 0, 0, 0);  stage(BT, bn, 65536, 0, 0, 0);
  stage(A, bm, 0, 0, 1, 0);  stage(BT, bn, 65536, 0, 1, 0);
  stage(A, bm, 0, 1, 0, 1);  stage(BT, bn, 65536, 1, 0, 1);
  VMW(8);
  __builtin_amdgcn_s_barrier();

  for (int kt = 0; kt < NT - 2; ++kt) {
    const int buf = kt & 1, nbuf = buf ^ 1;
    rd03(buf, 0);
    stage(A, bm, 0, nbuf, 1, kt + 1);
    GBAR; mf_lo(); GBAR;
    rd47(buf, 0);
    stage(BT, bn, 65536, nbuf, 1, kt + 1);
    GBAR; mf_hi(); VMW(8); __builtin_amdgcn_s_barrier();
    rd03(buf, 1);
    stage(A, bm, 0, buf, 0, kt + 2);
    stage(BT, bn, 65536, buf, 0, kt + 2);
    GBAR; mf_lo(); GBAR;
    rd47(buf, 1);
    GBAR; mf_hi(); VMW(8); __builtin_amdgcn_s_barrier();
  }
  {
    const int kt = NT - 2;
    const int buf = kt & 1, nbuf = buf ^ 1;
    rd03(buf, 0);
    stage(A, bm, 0, nbuf, 1, kt + 1);
    GBAR; mf_lo(); GBAR;
    rd47(buf, 0);
    stage(BT, bn, 65536, nbuf, 1, kt + 1);
    GBAR; mf_hi(); VMW(8); __builtin_amdgcn_s_barrier();
    rd03(buf, 1);
    GBAR; mf_lo(); GBAR;
    rd47(buf, 1);
    GBAR; mf_hi(); VMW(4); __builtin_amdgcn_s_barrier();
  }
  {
    const int buf = (NT - 1) & 1;
    rd03(buf, 0);
    GBAR; mf_lo(); GBAR;
    rd47(buf, 0);
    GBAR; mf_hi(); VMW(0); __builtin_amdgcn_s_barrier();
    rd03(buf, 1);
    GBAR; mf_lo(); GBAR;
    rd47(buf, 1);
    GBAR; mf_hi(); __builtin_amdgcn_s_barrier();
  }
#undef GBAR
#undef VMW

#pragma unroll
  for (int m = 0; m < 8; ++m)
#pragma unroll
    for (int n = 0; n < 4; ++n)
#pragma unroll
      for (int rr = 0; rr < 4; ++rr) {
        int row = bm + wr * 128 + m * 16 + l4 * 4 + rr;
        int col = bn + wc * 64 + n * 16 + l15;
        size_t ix = (size_t)row * N + col;
        float v = acc[m][n][rr];
        if (EPI == 0)      ((float*)Cout)[ix] = v;
        else if (EPI == 1) ((float*)Cout)[ix] = v + R[ix];
        else               ((bf16*)Cout)[ix] = (bf16)v;
      }
}

// ---------------- 128x128 8-wave deep-pipeline GEMM (qkv, w13) ----------------
// EPI 3: fused silu -> gate bf16 (LDS-pack).
// EPI 4: qkv fused post: cols 0-1023 -> bf16 to qkv; 1024-1279 -> rope -> k_r;
//        1280-1535 -> transposed -> vT.
template <int EPI>
__global__ __launch_bounds__(512, 4) void gemm8_bt(const bf16* __restrict__ A,
                                                   const bf16* __restrict__ BT,
                                                   void* __restrict__ Cout,
                                                   const float* __restrict__ tab,
                                                   bf16* __restrict__ krout,
                                                   bf16* __restrict__ vtout,
                                                   int N, int K) {
  extern __shared__ char smem[];   // 65536
  const int t = threadIdx.x;
  const int wid = t >> 6, l = t & 63;
  const int l15 = l & 15, l4 = l >> 4;
  const int wr = wid >> 1, wc = wid & 1;
  const int rsw = (l4 ^ ((l15 >> 1) & 3)) * 16;
  const int csw = ((t & 3) ^ ((t >> 3) & 3)) * 8;

  int nwg = gridDim.x;
  int q = nwg >> 3;
  int xcd = blockIdx.x & 7, jj = blockIdx.x >> 3;
  int L = xcd * q + jj;
  const int bm = (L & 15) * 128, bn = (L >> 4) * 128;

  const int NT = K >> 6;

  auto stage = [&](const bf16* __restrict__ G, int rowbase, int obase, int buf, int kc, int kt) {
    const bf16* src = G + (size_t)(rowbase + (t >> 2)) * K + kt * 64 + kc * 32 + csw;
    __builtin_amdgcn_global_load_lds(
        (const __attribute__((address_space(1))) void*)src,
        (__attribute__((address_space(3))) void*)(smem + obase + buf * 16384 + kc * 8192 +
                                                  wid * 1024),
        16, 0, 0);
  };
  auto ldA = [&](int buf, int kc, int m) -> bf16x8 {
    return *(const bf16x8*)(smem + buf * 16384 + kc * 8192 +
                            (wr * 32 + m * 16 + l15) * 64 + rsw);
  };
  auto ldB = [&](int buf, int kc, int n) -> bf16x8 {
    return *(const bf16x8*)(smem + 32768 + buf * 16384 + kc * 8192 +
                            (wc * 64 + n * 16 + l15) * 64 + rsw);
  };

  f32x4 acc[2][4] = {};
  bf16x8 af[2], bq[4];

  auto rdph = [&](int buf, int kc) {
#pragma unroll
    for (int m = 0; m < 2; ++m) af[m] = ldA(buf, kc, m);
#pragma unroll
    for (int n = 0; n < 4; ++n) bq[n] = ldB(buf, kc, n);
  };
  auto mf = [&]() {
    __builtin_amdgcn_s_setprio(1);
#pragma unroll
    for (int m = 0; m < 2; ++m)
#pragma unroll
      for (int n = 0; n < 4; ++n)
        acc[m][n] = __builtin_amdgcn_mfma_f32_16x16x32_bf16(af[m], bq[n], acc[m][n], 0, 0, 0);
    __builtin_amdgcn_s_setprio(0);
    __builtin_amdgcn_sched_barrier(0);
  };
#define SCB __builtin_amdgcn_sched_barrier(0)
#define VMW4 { asm volatile("s_waitcnt vmcnt(4)" ::: "memory"); SCB; }
#define VMW2 { asm volatile("s_waitcnt vmcnt(2)" ::: "memory"); SCB; }
#define VMW0 { asm volatile("s_waitcnt vmcnt(0)" ::: "memory"); SCB; }
#define SBAR { __builtin_amdgcn_s_barrier(); SCB; }

  stage(A, bm, 0, 0, 0, 0);  stage(BT, bn, 32768, 0, 0, 0);
  stage(A, bm, 0, 0, 1, 0);  stage(BT, bn, 32768, 0, 1, 0);
  stage(A, bm, 0, 1, 0, 1);  stage(BT, bn, 32768, 1, 0, 1);
  VMW4; __builtin_amdgcn_s_barrier();

  for (int kt = 0; kt < NT - 2; ++kt) {
    const int buf = kt & 1, nbuf = buf ^ 1;
    rdph(buf, 0);
    stage(A, bm, 0, nbuf, 1, kt + 1);
    stage(BT, bn, 32768, nbuf, 1, kt + 1);
    SCB; mf(); VMW4; SBAR;
    rdph(buf, 1);
    stage(A, bm, 0, buf, 0, kt + 2);
    stage(BT, bn, 32768, buf, 0, kt + 2);
    SCB; mf(); VMW4; SBAR;
  }
  {
    const int buf = (NT - 2) & 1, nbuf = buf ^ 1;
    rdph(buf, 0);
    stage(A, bm, 0, nbuf, 1, NT - 1);
    stage(BT, bn, 32768, nbuf, 1, NT - 1);
    SCB; mf(); VMW4; SBAR;
    rdph(buf, 1);
    SCB; mf(); VMW2; SBAR;
  }
  {
    const int buf = (NT - 1) & 1;
    rdph(buf, 0);
    SCB; mf(); VMW0; SBAR;
    rdph(buf, 1);
    SCB; mf();
  }
#undef SCB
#undef VMW4
#undef VMW2
#undef VMW0
#undef SBAR

  __builtin_amdgcn_s_barrier();   // all waves done with LDS slabs -> safe to alias

  if (EPI == 3) {
    bf16* wb = (bf16*)(smem + wid * 2304);     // 16 x 40 bf16
    bf16* G = (bf16*)Cout;
    const int Nc = N >> 1;
#pragma unroll
    for (int m = 0; m < 2; ++m) {
#pragma unroll
      for (int n = 0; n < 4; ++n)
#pragma unroll
        for (int rr = 0; rr < 4; ++rr) {
          float v = acc[m][n][rr];
          float part = __shfl_xor(v, 1, 64);
          if (!(l15 & 1)) {
            float s = v / (1.0f + __expf(-v));
            wb[(l4 * 4 + rr) * 40 + n * 8 + (l15 >> 1)] = (bf16)(s * part);
          }
        }
      LGKM0;
      int ROW = l >> 2, CB = l & 3;
      bf16x8 g = *(const bf16x8*)&wb[ROW * 40 + CB * 8];
      LGKM0;
      int row = bm + wr * 32 + m * 16 + ROW;
      int col = (bn >> 1) + wc * 32 + CB * 8;
      *(bf16x8*)&G[(size_t)row * Nc + col] = g;
    }
  } else {   // EPI == 4
    const int cb = bn >> 7;    // 0..11
    if (cb >= 10) {
      bf16* wbT = (bf16*)(smem + wid * 4352);
#pragma unroll
      for (int m = 0; m < 2; ++m)
#pragma unroll
        for (int n = 0; n < 4; ++n)
#pragma unroll
          for (int rr = 0; rr < 4; ++rr)
            wbT[(n * 16 + l15) * 34 + m * 16 + l4 * 4 + rr] = (bf16)acc[m][n][rr];
      LGKM0;
      bf16x8 v0 = *(const bf16x8*)&wbT[l * 34];
      bf16x8 v1 = *(const bf16x8*)&wbT[l * 34 + 8];
      bf16x8 v2 = *(const bf16x8*)&wbT[l * 34 + 16];
      bf16x8 v3 = *(const bf16x8*)&wbT[l * 34 + 24];
      LGKM0;
      int hh = ((bn - 1280) >> 6) + wc;
      int b = bm >> 10;
      int scol = (bm & 1023) + wr * 32;
      bf16* dst = &vtout[((size_t)((b * HK_ + hh) * 64 + l)) * S_ + scol];
      *(bf16x8*)&dst[0]  = v0;  *(bf16x8*)&dst[8]  = v1;
      *(bf16x8*)&dst[16] = v2;  *(bf16x8*)&dst[24] = v3;
    } else {
      bf16* wb = (bf16*)(smem + wid * 2304);
#pragma unroll
      for (int m = 0; m < 2; ++m) {
#pragma unroll
        for (int n = 0; n < 4; ++n)
#pragma unroll
          for (int rr = 0; rr < 4; ++rr)
            wb[(l4 * 4 + rr) * 72 + n * 16 + l15] = (bf16)acc[m][n][rr];
        LGKM0;
        int ROW = l >> 2, CB = l & 3;
        bf16x8 g0 = *(const bf16x8*)&wb[ROW * 72 + CB * 16];
        bf16x8 g1 = *(const bf16x8*)&wb[ROW * 72 + CB * 16 + 8];
        LGKM0;
        int row = bm + wr * 32 + m * 16 + ROW;
        if (cb < 8) {
          bf16* Cb = (bf16*)Cout;
          int col = bn + wc * 64 + CB * 16;
          *(bf16x8*)&Cb[(size_t)row * N + col] = g0;
          *(bf16x8*)&Cb[(size_t)row * N + col + 8] = g1;
        } else {
          int b = row >> 10, ss = row & 1023;
          int hh = ((bn - 1024) >> 6) + wc;
          int d0 = CB * 16;
          f32x4 t0 = *(const f32x4*)&tab[(ss * 32 + (d0 >> 1)) * 2];
          f32x4 t1 = *(const f32x4*)&tab[(ss * 32 + (d0 >> 1)) * 2 + 4];
          f32x4 t2 = *(const f32x4*)&tab[(ss * 32 + (d0 >> 1) + 4) * 2];
          f32x4 t3 = *(const f32x4*)&tab[(ss * 32 + (d0 >> 1) + 4) * 2 + 4];
          bf16x8 r0, r1;
#pragma unroll
          for (int j = 0; j < 4; ++j) {
            float a = (float)g0[2 * j], bv = (float)g0[2 * j + 1];
            float c  = (j < 2 ? t0 : t1)[(j & 1) * 2];
            float sn = (j < 2 ? t0 : t1)[(j & 1) * 2 + 1];
            r0[2 * j]     = (bf16)(a * c - bv * sn);
            r0[2 * j + 1] = (bf16)(a * sn + bv * c);
            float a2 = (float)g1[2 * j], bv2 = (float)g1[2 * j + 1];
            float c2  = (j < 2 ? t2 : t3)[(j & 1) * 2];
            float sn2 = (j < 2 ? t2 : t3)[(j & 1) * 2 + 1];
            r1[2 * j]     = (bf16)(a2 * c2 - bv2 * sn2);
            r1[2 * j + 1] = (bf16)(a2 * sn2 + bv2 * c2);
          }
          bf16* dst = &krout[((size_t)((b * HK_ + hh) * S_ + ss)) * 64 + d0];
          *(bf16x8*)&dst[0] = r0;
          *(bf16x8*)&dst[8] = r1;
        }
      }
    }
  }
}

// ---------------- flash attention (causal, GQA), KVBLK=128, in-register rope-Q ----------------
// + deferred l_run reduction
__global__ __launch_bounds__(256) void attn_k(const bf16* __restrict__ qkv,
                                              const float* __restrict__ tab,
                                              const bf16* __restrict__ k_r,
                                              const bf16* __restrict__ vT,
                                              bf16* __restrict__ o) {
  __shared__ bf16 k_lds[128 * 64];
  __shared__ bf16 v_lds[64 * 128];
  __shared__ bf16 p_lds[4][16 * 136];
  int t = threadIdx.x, w = t >> 6, l = t & 63, l15 = l & 15, l4 = l >> 4;
  int bx = blockIdx.x;
  int qt = bx & 15;
  if (bx >= 256) qt = 15 - qt;
  int head = (bx >> 4) & 15, b = bx >> 8;
  int kvh = head >> 2;
  const bf16* kh = k_r + ((size_t)(b * HK_ + kvh)) * S_ * 64;
  const bf16* vh = vT + ((size_t)(b * HK_ + kvh)) * 64 * S_;
  int q0 = qt * 64 + w * 16;
  const int ntile = (qt + 2) >> 1;

  bf16x8 aq[2];
  {
    int s = q0 + l15;
#pragma unroll
    for (int kc = 0; kc < 2; ++kc) {
      bf16x8 raw = *(const bf16x8*)&qkv[(size_t)(b * S_ + s) * 1536 + head * 64 +
                                        kc * 32 + l4 * 8];
      int d0 = kc * 16 + l4 * 4;
      f32x4 tc0 = *(const f32x4*)&tab[(s * 32 + d0) * 2];
      f32x4 tc1 = *(const f32x4*)&tab[(s * 32 + d0) * 2 + 4];
      bf16x8 out;
#pragma unroll
      for (int j = 0; j < 4; ++j) {
        float a = (float)raw[2 * j], bb = (float)raw[2 * j + 1];
        float c  = (j < 2 ? tc0 : tc1)[(j & 1) * 2];
        float sn = (j < 2 ? tc0 : tc1)[(j & 1) * 2 + 1];
        out[2 * j]     = (bf16)((a * c - bb * sn) * 0.125f);
        out[2 * j + 1] = (bf16)((a * sn + bb * c) * 0.125f);
      }
      aq[kc] = out;
    }
  }

  f32x4 acc_o[4] = {};
  float m_run[4], l_run[4];
#pragma unroll
  for (int r = 0; r < 4; ++r) { m_run[r] = -1e30f; l_run[r] = 0.f; }

  bf16x8 gk[4], gv[4];
#pragma unroll
  for (int i = 0; i < 4; ++i) {
    int c = i * 256 + t;
    gk[i] = *(const bf16x8*)&kh[(size_t)(c >> 3) * 64 + (c & 7) * 8];
    gv[i] = *(const bf16x8*)&vh[(size_t)(c >> 4) * S_ + (c & 15) * 8];
  }

  for (int j = 0; j < ntile; ++j) {
#pragma unroll
    for (int i = 0; i < 4; ++i) {
      int c = i * 256 + t;
      int krow = c >> 3, kch = (c & 7) ^ (krow & 7);
      *(bf16x8*)&k_lds[krow * 64 + kch * 8] = gk[i];
      int vrow = c >> 4, vch = (c & 15) ^ (vrow & 15);
      *(bf16x8*)&v_lds[vrow * 128 + vch * 8] = gv[i];
    }
    __syncthreads();

    bf16x8 gkn[4], gvn[4];
    if (j + 1 < ntile) {
#pragma unroll
      for (int i = 0; i < 4; ++i) {
        int c = i * 256 + t;
        gkn[i] = *(const bf16x8*)&kh[(size_t)((j + 1) * 128 + (c >> 3)) * 64 + (c & 7) * 8];
        gvn[i] = *(const bf16x8*)&vh[(size_t)(c >> 4) * S_ + (j + 1) * 128 + (c & 15) * 8];
      }
    }

    f32x4 sc[8];
#pragma unroll
    for (int nt = 0; nt < 8; ++nt) {
      f32x4 a = {};
#pragma unroll
      for (int kc = 0; kc < 2; ++kc) {
        bf16x8 bk = *(const bf16x8*)&k_lds[(nt * 16 + l15) * 64 +
                                           (((kc * 4 + l4) ^ (l15 & 7)) * 8)];
        a = __builtin_amdgcn_mfma_f32_16x16x32_bf16(aq[kc], bk, a, 0, 0, 0);
      }
      sc[nt] = a;
    }

    bool lastt = (j == ntile - 1);
#pragma unroll
    for (int r = 0; r < 4; ++r) {
      float pmax = -1e30f;
#pragma unroll
      for (int nt = 0; nt < 8; ++nt) {
        float s = sc[nt][r];
        if (lastt) {
          int kj = j * 128 + nt * 16 + l15;
          int qi = q0 + l4 * 4 + r;
          if (kj > qi) s = -1e30f;
        }
        sc[nt][r] = s;
        pmax = fmaxf(pmax, s);
      }
      if (!__all(pmax <= m_run[r] + 8.0f)) {
        float mx = pmax;
        mx = fmaxf(mx, __shfl_xor(mx, 1, 64));
        mx = fmaxf(mx, __shfl_xor(mx, 2, 64));
        mx = fmaxf(mx, __shfl_xor(mx, 4, 64));
        mx = fmaxf(mx, __shfl_xor(mx, 8, 64));
        float mn = fmaxf(m_run[r], mx);
        float scale = __expf(m_run[r] - mn);
        m_run[r] = mn;
        l_run[r] *= scale;
#pragma unroll
        for (int nt = 0; nt < 4; ++nt) acc_o[nt][r] *= scale;
      }
      float rs = 0.f;
#pragma unroll
      for (int nt = 0; nt < 8; ++nt) {
        float p = __expf(sc[nt][r] - m_run[r]);
        sc[nt][r] = p;
        rs += p;
      }
      l_run[r] += rs;
    }

#pragma unroll
    for (int nt = 0; nt < 8; ++nt)
#pragma unroll
      for (int r = 0; r < 4; ++r)
        p_lds[w][(l4 * 4 + r) * 136 + nt * 16 + l15] = (bf16)sc[nt][r];
    LGKM0;

#pragma unroll
    for (int kc = 0; kc < 4; ++kc) {
      bf16x8 pf = *(const bf16x8*)&p_lds[w][l15 * 136 + kc * 32 + l4 * 8];
#pragma unroll
      for (int nt = 0; nt < 4; ++nt) {
        bf16x8 vf = *(const bf16x8*)&v_lds[(nt * 16 + l15) * 128 +
                                           (((kc * 4 + l4) ^ l15) * 8)];
        acc_o[nt] = __builtin_amdgcn_mfma_f32_16x16x32_bf16(pf, vf, acc_o[nt], 0, 0, 0);
      }
    }
    __syncthreads();

#pragma unroll
    for (int i = 0; i < 4; ++i) { gk[i] = gkn[i]; gv[i] = gvn[i]; }
  }

#pragma unroll
  for (int r = 0; r < 4; ++r) {
    float lr = l_run[r];
    lr += __shfl_xor(lr, 1, 64);
    lr += __shfl_xor(lr, 2, 64);
    lr += __shfl_xor(lr, 4, 64);
    lr += __shfl_xor(lr, 8, 64);
    l_run[r] = lr;
  }

#pragma unroll
  for (int nt = 0; nt < 4; ++nt)
#pragma unroll
    for (int r = 0; r < 4; ++r) {
      float ov = acc_o[nt][r] / l_run[r];
      int s = qt * 64 + w * 16 + l4 * 4 + r;
      o[((size_t)(b * S_ + s)) * D_ + head * 64 + nt * 16 + l15] = (bf16)ov;
    }
}

// =======================================================================
extern "C" void kernel_launch(void* const* d_in, const int* in_sizes, int n_in,
                              void* d_out, int out_size, void* d_ws, size_t ws_size,
                              hipStream_t stream) {
  const int* tokens  = (const int*)d_in[0];
  const float* tok_emb = (const float*)d_in[2];
  const float* wq = (const float*)d_in[3];
  const float* wk = (const float*)d_in[4];
  const float* wv = (const float*)d_in[5];
  const float* wo = (const float*)d_in[6];
  const float* w1 = (const float*)d_in[7];
  const float* w2 = (const float*)d_in[8];
  const float* w3 = (const float*)d_in[9];
  const float* anw = (const float*)d_in[10];
  const float* fnw = (const float*)d_in[11];
  const float* finw = (const float*)d_in[12];
  const float* outw = (const float*)d_in[13];

  (void)hipFuncSetAttribute((const void*)gemm256_bt<0>,
                            hipFuncAttributeMaxDynamicSharedMemorySize, 131072);
  (void)hipFuncSetAttribute((const void*)gemm8_bt<3>,
                            hipFuncAttributeMaxDynamicSharedMemorySize, 65536);
  (void)hipFuncSetAttribute((const void*)gemm8_bt<4>,
                            hipFuncAttributeMaxDynamicSharedMemorySize, 65536);

  auto al = [](size_t x) { return (x + 255) & ~(size_t)255; };
  const size_t WTB   = 11272192ull * 2;
  const size_t OUTWTB = (size_t)V_ * D_ * 2;
  const size_t HB   = (size_t)B_ * S_ * D_ * 4;
  const size_t XBB  = (size_t)B_ * S_ * D_ * 2;
  const size_t QKVB = (size_t)B_ * S_ * 1536 * 2;
  const size_t KRB  = (size_t)B_ * HK_ * S_ * 64 * 2;
  const size_t OB   = (size_t)B_ * S_ * D_ * 2;
  const size_t GATEB = (size_t)B_ * S_ * 2816 * 2;
  const size_t TABB = (size_t)S_ * 32 * 2 * 4;
  const size_t PARTB = (size_t)B_ * S_ * D_ * 4 * 2;

  size_t fixed = al(OUTWTB) + al(HB) + al(XBB) + al(QKVB) + al(KRB) + al(KRB) +
                 al(OB) + al(GATEB) + al(TABB) + al(PARTB);
  bool allup = ws_size >= fixed + 8 * al(WTB) + 4096;
  int nslots = allup ? 8 : 1;

  char* p = (char*)d_ws;
  bf16* wT    = (bf16*)p; p += (size_t)nslots * al(WTB);
  bf16* outwT = (bf16*)p; p += al(OUTWTB);
  float* h    = (float*)p; p += al(HB);
  bf16* xb    = (bf16*)p; p += al(XBB);
  bf16* qkv   = (bf16*)p; p += al(QKVB);
  bf16* k_r   = (bf16*)p; p += al(KRB);
  bf16* vTb   = (bf16*)p; p += al(KRB);
  bf16* ob    = (bf16*)p; p += al(OB);
  bf16* gate  = (bf16*)p; p += al(GATEB);
  float* tab  = (float*)p; p += al(TABB);
  float* part = (float*)p; p += al(PARTB);

  const size_t WTS = al(WTB) / 2;

  auto tr = [&](const float* src, size_t srcStride, bf16* dst, size_t dstStride,
                int Kd, int Nd, int layers, int rowMul, int rowAdd) {
    transpose_cvt<<<dim3(Nd / 64, Kd / 64, layers), 256, 0, stream>>>(
        src, dst, Kd, Nd, (long long)srcStride, (long long)dstStride, rowMul, rowAdd);
  };

  if (allup) {
    // single mega-dispatch: rope table + embed/rms + all weight transposes
    setup_k<<<32192, 256, 0, stream>>>(tokens, tok_emb, anw, h, xb, tab,
                                       outw, outwT, wq, wk, wv, wo, w1, w3, w2,
                                       wT, (long long)WTS);
  } else {
    ropetab_k<<<128, 256, 0, stream>>>(tab);
    embedrms_k<<<B_ * S_, 256, 0, stream>>>(tokens, tok_emb, anw, h, xb);
    tr(outw, 0, outwT, 0, 1024, 32000, 1, 1, 0);
  }

  for (int l = 0; l < L_; ++l) {
    bf16* wtl = wT + (allup ? (size_t)l * WTS : 0);
    if (!allup) {
      tr(wq + (size_t)l * 1024 * 1024, 0, wtl + OFFD_QKV, 0, 1024, 1024, 1, 1, 0);
      tr(wk + (size_t)l * 1024 * 256,  0, wtl + OFFD_WK,  0, 1024, 256, 1, 1, 0);
      tr(wv + (size_t)l * 1024 * 256,  0, wtl + OFFD_WV,  0, 1024, 256, 1, 1, 0);
      tr(wo + (size_t)l * 1024 * 1024, 0, wtl + OFFD_WO,  0, 1024, 1024, 1, 1, 0);
      tr(w1 + (size_t)l * 1024 * 2816, 0, wtl + OFFD_W13, 0, 1024, 2816, 1, 2, 0);
      tr(w3 + (size_t)l * 1024 * 2816, 0, wtl + OFFD_W13, 0, 1024, 2816, 1, 2, 1);
      tr(w2 + (size_t)l * 2816 * 1024, 0, wtl + OFFD_W2,  0, 2816, 1024, 1, 1, 0);
    }

    gemm8_bt<4><<<192, 512, 65536, stream>>>(xb, wtl + OFFD_QKV, qkv, tab, k_r, vTb,
                                             1536, 1024);
    attn_k<<<B_ * HQ_ * (S_ / 64), 256, 0, stream>>>(qkv, tab, k_r, vTb, ob);
    gemm_bt<1, 32><<<dim3(64, 8, 1), 256, 0, stream>>>(ob, wtl + OFFD_WO, h, h,
                                                       2048, 1024, 1024, 1024, 1024, 0, 0);
    rmsnorm_k<<<B_ * S_, 256, 0, stream>>>(h, fnw + l * D_, xb);
    gemm8_bt<3><<<704, 512, 65536, stream>>>(xb, wtl + OFFD_W13, gate, nullptr, nullptr,
                                             nullptr, 5632, 1024);
    gemm_bt<0, 64><<<dim3(32, 8, 2), 256, 0, stream>>>(gate, wtl + OFFD_W2, part, nullptr,
                                                       2048, 1024, 1408, 2816, 2816,
                                                       1408, 2097152ll);
    redrms_k<<<B_ * S_, 256, 0, stream>>>(part, h,
                                          (l < L_ - 1) ? (anw + (l + 1) * D_) : finw, xb);
  }

  gemm256_bt<0><<<1000, 512, 131072, stream>>>(xb, outwT, d_out, nullptr, 32000, 1024);
}

// Round 19
// 1433.095 us; speedup vs baseline: 1.0050x; 1.0050x over previous
//
#include <hip/hip_runtime.h>
#include <hip/hip_bf16.h>

typedef __bf16 bf16;
typedef __bf16 bf16x8 __attribute__((ext_vector_type(8)));
typedef float f32x4 __attribute__((ext_vector_type(4)));

#define B_ 2
#define S_ 1024
#define D_ 1024
#define L_ 8
#define HQ_ 16
#define HK_ 4
#define DH_ 64
#define FF_ 2816
#define V_ 32000

#define OFFD_QKV 0
#define OFFD_WK  1048576
#define OFFD_WV  1310720
#define OFFD_WO  1572864
#define OFFD_W13 2621440
#define OFFD_W2  8388608

#define LGKM0 { asm volatile("s_waitcnt lgkmcnt(0)" ::: "memory"); __builtin_amdgcn_sched_barrier(0); }

// Swizzled 64x64 f32 transpose tile helpers:
//   write: f32x4 at row r, logical chunk ch -> phys chunk ch ^ ((r>>3)&7)
//   read : scalar col n of row -> phys col (((n>>2) ^ ((row>>3)&7))<<2) | (n&3)
// Read bank = 4*((n>>2)^(row>>3)) + (n&3): 2 lanes/bank (free). 16 KB LDS.

// ---------------- mega setup: rope-table + embed/rms + ALL weight transposes ----------------
// segments (blockIdx.x): [0,128) rope | [128,2176) embed+rms | then transpose tiles:
// outw 8000 | wq 2048 | wk 512 | wv 512 | wo 2048 | w1 5632 | w3 5632 | w2 5632 = 32192 total
__global__ __launch_bounds__(256) void setup_k(const int* __restrict__ toks,
                                               const float* __restrict__ emb,
                                               const float* __restrict__ anw0,
                                               float* __restrict__ h,
                                               bf16* __restrict__ xb,
                                               float* __restrict__ tab,
                                               const float* __restrict__ outw,
                                               bf16* __restrict__ outwT,
                                               const float* __restrict__ wq,
                                               const float* __restrict__ wk,
                                               const float* __restrict__ wv,
                                               const float* __restrict__ wo,
                                               const float* __restrict__ w1,
                                               const float* __restrict__ w3,
                                               const float* __restrict__ w2,
                                               bf16* __restrict__ wT,
                                               long long WTS) {
  __shared__ float tile[64][64];
  __shared__ float partial[4];
  int id = blockIdx.x, t = threadIdx.x;

  if (id < 128) {                       // rope table
    int i = id * 256 + t;
    int d = i & 31, s = i >> 5;
    float f = expf(-(2.0f * d / 64.0f) * logf(500000.0f));
    float ang = (float)s * f;
    tab[i * 2]     = cosf(ang);
    tab[i * 2 + 1] = sinf(ang);
    return;
  }
  id -= 128;
  if (id < 2048) {                      // embed + layer-0 rmsnorm
    int row = id;
    int tok = toks[row];
    int base = t * 4;
    f32x4 v = *(const f32x4*)&emb[(size_t)tok * D_ + base];
    *(f32x4*)&h[(size_t)row * D_ + base] = v;
    float ss = v[0]*v[0] + v[1]*v[1] + v[2]*v[2] + v[3]*v[3];
    for (int m = 1; m < 64; m <<= 1) ss += __shfl_xor(ss, m, 64);
    if ((t & 63) == 0) partial[t >> 6] = ss;
    __syncthreads();
    float tot = partial[0] + partial[1] + partial[2] + partial[3];
    float rr = rsqrtf(tot * (1.0f / D_) + 1e-5f);
    f32x4 wv4 = *(const f32x4*)&anw0[base];
    bf16* o = xb + (size_t)row * D_ + base;
    o[0] = (bf16)(v[0] * rr * wv4[0]);
    o[1] = (bf16)(v[1] * rr * wv4[1]);
    o[2] = (bf16)(v[2] * rr * wv4[2]);
    o[3] = (bf16)(v[3] * rr * wv4[3]);
    return;
  }
  id -= 2048;

  const float* src; bf16* dst; int K, N, rowMul, rowAdd, bx, by;
  if (id < 8000) {                      // outw: 1024 x 32000
    src = outw; dst = outwT; K = 1024; N = 32000; rowMul = 1; rowAdd = 0;
    bx = id % 500; by = id / 500;
  } else if ((id -= 8000) < 2048) {     // wq
    int z = id >> 8, r2 = id & 255;
    src = wq + (size_t)z * 1048576; dst = wT + (size_t)z * WTS + OFFD_QKV;
    K = 1024; N = 1024; rowMul = 1; rowAdd = 0; bx = r2 & 15; by = r2 >> 4;
  } else if ((id -= 2048) < 512) {      // wk
    int z = id >> 6, r2 = id & 63;
    src = wk + (size_t)z * 262144; dst = wT + (size_t)z * WTS + OFFD_WK;
    K = 1024; N = 256; rowMul = 1; rowAdd = 0; bx = r2 & 3; by = r2 >> 2;
  } else if ((id -= 512) < 512) {       // wv
    int z = id >> 6, r2 = id & 63;
    src = wv + (size_t)z * 262144; dst = wT + (size_t)z * WTS + OFFD_WV;
    K = 1024; N = 256; rowMul = 1; rowAdd = 0; bx = r2 & 3; by = r2 >> 2;
  } else if ((id -= 512) < 2048) {      // wo
    int z = id >> 8, r2 = id & 255;
    src = wo + (size_t)z * 1048576; dst = wT + (size_t)z * WTS + OFFD_WO;
    K = 1024; N = 1024; rowMul = 1; rowAdd = 0; bx = r2 & 15; by = r2 >> 4;
  } else if ((id -= 2048) < 5632) {     // w1 (interleaved even rows)
    int z = id / 704, r2 = id % 704;
    src = w1 + (size_t)z * 2883584; dst = wT + (size_t)z * WTS + OFFD_W13;
    K = 1024; N = 2816; rowMul = 2; rowAdd = 0; bx = r2 % 44; by = r2 / 44;
  } else if ((id -= 5632) < 5632) {     // w3 (interleaved odd rows)
    int z = id / 704, r2 = id % 704;
    src = w3 + (size_t)z * 2883584; dst = wT + (size_t)z * WTS + OFFD_W13;
    K = 1024; N = 2816; rowMul = 2; rowAdd = 1; bx = r2 % 44; by = r2 / 44;
  } else {                              // w2
    id -= 5632;
    int z = id / 704, r2 = id % 704;
    src = w2 + (size_t)z * 2883584; dst = wT + (size_t)z * WTS + OFFD_W2;
    K = 2816; N = 1024; rowMul = 1; rowAdd = 0; bx = r2 & 15; by = r2 >> 4;
  }

#pragma unroll
  for (int it = 0; it < 4; ++it) {
    int idx = it * 256 + t;
    int r = idx >> 4, ch = idx & 15;
    f32x4 v = *(const f32x4*)&src[(size_t)(by * 64 + r) * N + bx * 64 + ch * 4];
    int chs = ch ^ ((r >> 3) & 7);
    *(f32x4*)&tile[r][chs * 4] = v;
  }
  __syncthreads();
#pragma unroll
  for (int it = 0; it < 2; ++it) {
    int idx = it * 256 + t;
    int n = idx >> 3, k8 = (idx & 7) * 8;
    const int sw = idx & 7;                       // (row>>3)&7 for rows k8..k8+7
    const int phys = (((n >> 2) ^ sw) << 2) | (n & 3);
    bf16x8 o;
#pragma unroll
    for (int j = 0; j < 8; ++j) o[j] = (bf16)tile[k8 + j][phys];
    *(bf16x8*)&dst[(size_t)((bx * 64 + n) * rowMul + rowAdd) * K + by * 64 + k8] = o;
  }
}

// ---------------- fallback kernels (!allup path) ----------------
__global__ __launch_bounds__(256) void ropetab_k(float* __restrict__ tab) {
  int i = blockIdx.x * 256 + threadIdx.x;
  if (i >= S_ * 32) return;
  int d = i & 31, s = i >> 5;
  float f = expf(-(2.0f * d / 64.0f) * logf(500000.0f));
  float ang = (float)s * f;
  tab[i * 2]     = cosf(ang);
  tab[i * 2 + 1] = sinf(ang);
}

__global__ __launch_bounds__(256) void embedrms_k(const int* __restrict__ toks,
                                                  const float* __restrict__ emb,
                                                  const float* __restrict__ w,
                                                  float* __restrict__ h,
                                                  bf16* __restrict__ out) {
  int row = blockIdx.x;
  int tok = toks[row];
  int base = threadIdx.x * 4;
  f32x4 v = *(const f32x4*)&emb[(size_t)tok * D_ + base];
  *(f32x4*)&h[(size_t)row * D_ + base] = v;
  float ss = v[0]*v[0] + v[1]*v[1] + v[2]*v[2] + v[3]*v[3];
  for (int m = 1; m < 64; m <<= 1) ss += __shfl_xor(ss, m, 64);
  __shared__ float partial[4];
  if ((threadIdx.x & 63) == 0) partial[threadIdx.x >> 6] = ss;
  __syncthreads();
  float tot = partial[0] + partial[1] + partial[2] + partial[3];
  float rr = rsqrtf(tot * (1.0f / D_) + 1e-5f);
  f32x4 wv = *(const f32x4*)&w[base];
  bf16* o = out + (size_t)row * D_ + base;
  o[0] = (bf16)(v[0] * rr * wv[0]);
  o[1] = (bf16)(v[1] * rr * wv[1]);
  o[2] = (bf16)(v[2] * rr * wv[2]);
  o[3] = (bf16)(v[3] * rr * wv[3]);
}

__global__ __launch_bounds__(256) void transpose_cvt(const float* __restrict__ src,
                                                     bf16* __restrict__ dst,
                                                     int K, int N,
                                                     long long srcStride, long long dstStride,
                                                     int rowMul, int rowAdd) {
  __shared__ float tile[64][64];
  int bx = blockIdx.x, by = blockIdx.y, z = blockIdx.z;
  src += (size_t)z * srcStride;
  dst += (size_t)z * dstStride;
  int t = threadIdx.x;
#pragma unroll
  for (int it = 0; it < 4; ++it) {
    int idx = it * 256 + t;
    int r = idx >> 4, ch = idx & 15;
    f32x4 v = *(const f32x4*)&src[(size_t)(by * 64 + r) * N + bx * 64 + ch * 4];
    int chs = ch ^ ((r >> 3) & 7);
    *(f32x4*)&tile[r][chs * 4] = v;
  }
  __syncthreads();
#pragma unroll
  for (int it = 0; it < 2; ++it) {
    int idx = it * 256 + t;
    int n = idx >> 3, k8 = (idx & 7) * 8;
    const int sw = idx & 7;
    const int phys = (((n >> 2) ^ sw) << 2) | (n & 3);
    bf16x8 o;
#pragma unroll
    for (int j = 0; j < 8; ++j) o[j] = (bf16)tile[k8 + j][phys];
    *(bf16x8*)&dst[(size_t)((bx * 64 + n) * rowMul + rowAdd) * K + by * 64 + k8] = o;
  }
}

// ---------------- rmsnorm: fp32 in -> bf16 out ----------------
__global__ __launch_bounds__(256) void rmsnorm_k(const float* __restrict__ x,
                                                 const float* __restrict__ w,
                                                 bf16* __restrict__ out) {
  int row = blockIdx.x;
  const float* xr = x + (size_t)row * D_;
  int base = threadIdx.x * 4;
  f32x4 v = *(const f32x4*)&xr[base];
  float ss = v[0]*v[0] + v[1]*v[1] + v[2]*v[2] + v[3]*v[3];
  for (int m = 1; m < 64; m <<= 1) ss += __shfl_xor(ss, m, 64);
  __shared__ float partial[4];
  if ((threadIdx.x & 63) == 0) partial[threadIdx.x >> 6] = ss;
  __syncthreads();
  float tot = partial[0] + partial[1] + partial[2] + partial[3];
  float rr = rsqrtf(tot * (1.0f / D_) + 1e-5f);
  f32x4 wv = *(const f32x4*)&w[base];
  bf16* o = out + (size_t)row * D_ + base;
  o[0] = (bf16)(v[0] * rr * wv[0]);
  o[1] = (bf16)(v[1] * rr * wv[1]);
  o[2] = (bf16)(v[2] * rr * wv[2]);
  o[3] = (bf16)(v[3] * rr * wv[3]);
}

// ---------------- fused split-K reduce + residual + rmsnorm ----------------
__global__ __launch_bounds__(256) void redrms_k(const float* __restrict__ p,
                                                float* __restrict__ h,
                                                const float* __restrict__ w,
                                                bf16* __restrict__ out) {
  int row = blockIdx.x;
  int base = threadIdx.x * 4;
  size_t ix = (size_t)row * D_ + base;
  f32x4 a = *(const f32x4*)&p[ix];
  f32x4 bb = *(const f32x4*)&p[ix + 2097152];
  f32x4 v = *(const f32x4*)&h[ix];
  v += a + bb;
  *(f32x4*)&h[ix] = v;
  float ss = v[0]*v[0] + v[1]*v[1] + v[2]*v[2] + v[3]*v[3];
  for (int m = 1; m < 64; m <<= 1) ss += __shfl_xor(ss, m, 64);
  __shared__ float partial[4];
  if ((threadIdx.x & 63) == 0) partial[threadIdx.x >> 6] = ss;
  __syncthreads();
  float tot = partial[0] + partial[1] + partial[2] + partial[3];
  float rr = rsqrtf(tot * (1.0f / D_) + 1e-5f);
  f32x4 wv = *(const f32x4*)&w[base];
  bf16* o = out + (size_t)row * D_ + base;
  o[0] = (bf16)(v[0] * rr * wv[0]);
  o[1] = (bf16)(v[1] * rr * wv[1]);
  o[2] = (bf16)(v[2] * rr * wv[2]);
  o[3] = (bf16)(v[3] * rr * wv[3]);
}

// ---------------- BMx128 2-phase GEMM (wo BM=32; w2 split-K BM=64) ----------------
template <int EPI, int BM>
__global__ __launch_bounds__(256) void gemm_bt(const bf16* __restrict__ A,
                                               const bf16* __restrict__ BT,
                                               void* __restrict__ Cout,
                                               const float* __restrict__ R,
                                               int M, int N, int K,
                                               int lda, int ldb,
                                               int zKoff, long long partStride) {
  constexpr int MR = BM / 32;
  __shared__ bf16 As[BM * 64];
  __shared__ bf16 Bs[128 * 64];
  const int t = threadIdx.x;
  const int w = t >> 6, l = t & 63;
  const int l15 = l & 15, l4 = l >> 4;
  const int bm = blockIdx.x * BM, bn = blockIdx.y * 128;
  const int wr = w >> 1, wc = w & 1;
  const int z = blockIdx.z;

  const bf16* Az = A + (size_t)z * zKoff;
  const bf16* Bz = BT + (size_t)z * zKoff;
  float* Cz = (float*)Cout + (size_t)z * partStride;

  const int srow = t >> 3, scol = (t & 7) * 8;
  const bf16* ag = &Az[(size_t)(bm + srow) * lda + scol];
  const bf16* bg = &Bz[(size_t)(bn + srow) * ldb + scol];
  const int ldsbase = (t & 192) * 8;

  f32x4 acc[MR][4] = {};

  for (int k0 = 0; k0 < K; k0 += 64) {
#pragma unroll
    for (int i = 0; i < BM / 32; ++i)
      __builtin_amdgcn_global_load_lds(
          (const __attribute__((address_space(1))) void*)(ag + (size_t)(i * 32) * lda + k0),
          (__attribute__((address_space(3))) void*)&As[i * 2048 + ldsbase], 16, 0, 0);
#pragma unroll
    for (int i = 0; i < 4; ++i)
      __builtin_amdgcn_global_load_lds(
          (const __attribute__((address_space(1))) void*)(bg + (size_t)(i * 32) * ldb + k0),
          (__attribute__((address_space(3))) void*)&Bs[i * 2048 + ldsbase], 16, 0, 0);
    __syncthreads();
#pragma unroll
    for (int kc = 0; kc < 2; ++kc) {
      bf16x8 af[MR], bfr[4];
#pragma unroll
      for (int m = 0; m < MR; ++m)
        af[m] = *(const bf16x8*)&As[(wr * (BM / 2) + m * 16 + l15) * 64 + kc * 32 + l4 * 8];
#pragma unroll
      for (int n = 0; n < 4; ++n)
        bfr[n] = *(const bf16x8*)&Bs[(wc * 64 + n * 16 + l15) * 64 + kc * 32 + l4 * 8];
#pragma unroll
      for (int m = 0; m < MR; ++m)
#pragma unroll
        for (int n = 0; n < 4; ++n)
          acc[m][n] = __builtin_amdgcn_mfma_f32_16x16x32_bf16(af[m], bfr[n], acc[m][n], 0, 0, 0);
    }
    __syncthreads();
  }

#pragma unroll
  for (int m = 0; m < MR; ++m)
#pragma unroll
    for (int n = 0; n < 4; ++n)
#pragma unroll
      for (int r = 0; r < 4; ++r) {
        int row = bm + wr * (BM / 2) + m * 16 + l4 * 4 + r;
        int col = bn + wc * 64 + n * 16 + l15;
        size_t ix = (size_t)row * N + col;
        float v = acc[m][n][r];
        if (EPI == 0)      Cz[ix] = v;
        else               Cz[ix] = v + R[ix];
      }
}

// ---------------- 256x256 8-phase GEMM, deep-pipeline S2 (logits; 1 tile/block) ----------------
template <int EPI>
__global__ __launch_bounds__(512, 2) void gemm256_bt(const bf16* __restrict__ A,
                                                     const bf16* __restrict__ BT,
                                                     void* __restrict__ Cout,
                                                     const float* __restrict__ R,
                                                     int N, int K) {
  extern __shared__ char smem[];   // 131072 B
  const int t = threadIdx.x;
  const int wid = t >> 6, l = t & 63;
  const int l15 = l & 15, l4 = l >> 4;
  const int wr = wid >> 2, wc = wid & 3;
  const int rsw = (l4 ^ ((l15 >> 1) & 3)) * 16;
  const int csw = ((t & 3) ^ ((t >> 3) & 3)) * 8;

  int nwg = gridDim.x;
  int q = nwg >> 3, r = nwg & 7;
  int xcd = blockIdx.x & 7, jj = blockIdx.x >> 3;
  int L = (xcd < r ? xcd * (q + 1) : r * (q + 1) + (xcd - r) * q) + jj;
  const int bm = (L & 7) * 256, bn = (L >> 3) * 256;

  const int NT = K >> 6;

  auto stage = [&](const bf16* __restrict__ G, int rowbase, int cbase, int buf, int kc, int kt) {
#pragma unroll
    for (int i = 0; i < 2; ++i) {
      int j = i * 512 + t;
      const bf16* src = G + (size_t)(rowbase + (j >> 2)) * K + kt * 64 + kc * 32 + csw;
      __builtin_amdgcn_global_load_lds(
          (const __attribute__((address_space(1))) void*)src,
          (__attribute__((address_space(3))) void*)(smem + cbase + buf * 32768 + kc * 16384 +
                                                    i * 8192 + wid * 1024),
          16, 0, 0);
    }
  };
  auto ldA = [&](int buf, int kc, int m) -> bf16x8 {
    return *(const bf16x8*)(smem + buf * 32768 + kc * 16384 +
                            (wr * 128 + m * 16 + l15) * 64 + rsw);
  };
  auto ldB = [&](int buf, int kc, int n) -> bf16x8 {
    return *(const bf16x8*)(smem + 65536 + buf * 32768 + kc * 16384 +
                            (wc * 64 + n * 16 + l15) * 64 + rsw);
  };

  f32x4 acc[8][4] = {};
  bf16x8 af[4], bq[4];

  auto rd03 = [&](int buf, int kc) {
#pragma unroll
    for (int m = 0; m < 4; ++m) af[m] = ldA(buf, kc, m);
#pragma unroll
    for (int n = 0; n < 4; ++n) bq[n] = ldB(buf, kc, n);
  };
  auto rd47 = [&](int buf, int kc) {
#pragma unroll
    for (int m = 0; m < 4; ++m) af[m] = ldA(buf, kc, 4 + m);
  };
  auto mf_lo = [&]() {
    __builtin_amdgcn_s_setprio(1);
#pragma unroll
    for (int m = 0; m < 4; ++m)
#pragma unroll
      for (int n = 0; n < 4; ++n)
        acc[m][n] = __builtin_amdgcn_mfma_f32_16x16x32_bf16(af[m], bq[n], acc[m][n], 0, 0, 0);
    __builtin_amdgcn_s_setprio(0);
    __builtin_amdgcn_sched_barrier(0);
  };
  auto mf_hi = [&]() {
    __builtin_amdgcn_s_setprio(1);
#pragma unroll
    for (int m = 0; m < 4; ++m)
#pragma unroll
      for (int n = 0; n < 4; ++n)
        acc[4 + m][n] = __builtin_amdgcn_mfma_f32_16x16x32_bf16(af[m], bq[n], acc[4 + m][n], 0, 0, 0);
    __builtin_amdgcn_s_setprio(0);
    __builtin_amdgcn_sched_barrier(0);
  };
#define GBAR { __builtin_amdgcn_sched_barrier(0); __builtin_amdgcn_s_barrier(); }
#define VMW(n) { asm volatile("s_waitcnt vmcnt(" #n ")" ::: "memory"); __builtin_amdgcn_sched_barrier(0); }

  stage(A, bm, 0, 0, 0, 0);  stage(BT, bn, 65536, 0, 0, 0);
  stage(A, bm, 0, 0, 1, 0);  stage(BT, bn, 65536, 0, 1, 0);
  stage(A, bm, 0, 1, 0, 1);  stage(BT, bn, 65536, 1, 0, 1);
  VMW(8);
  __builtin_amdgcn_s_barrier();

  for (int kt = 0; kt < NT - 2; ++kt) {
    const int buf = kt & 1, nbuf = buf ^ 1;
    rd03(buf, 0);
    stage(A, bm, 0, nbuf, 1, kt + 1);
    GBAR; mf_lo(); GBAR;
    rd47(buf, 0);
    stage(BT, bn, 65536, nbuf, 1, kt + 1);
    GBAR; mf_hi(); VMW(8); __builtin_amdgcn_s_barrier();
    rd03(buf, 1);
    stage(A, bm, 0, buf, 0, kt + 2);
    stage(BT, bn, 65536, buf, 0, kt + 2);
    GBAR; mf_lo(); GBAR;
    rd47(buf, 1);
    GBAR; mf_hi(); VMW(8); __builtin_amdgcn_s_barrier();
  }
  {
    const int kt = NT - 2;
    const int buf = kt & 1, nbuf = buf ^ 1;
    rd03(buf, 0);
    stage(A, bm, 0, nbuf, 1, kt + 1);
    GBAR; mf_lo(); GBAR;
    rd47(buf, 0);
    stage(BT, bn, 65536, nbuf, 1, kt + 1);
    GBAR; mf_hi(); VMW(8); __builtin_amdgcn_s_barrier();
    rd03(buf, 1);
    GBAR; mf_lo(); GBAR;
    rd47(buf, 1);
    GBAR; mf_hi(); VMW(4); __builtin_amdgcn_s_barrier();
  }
  {
    const int buf = (NT - 1) & 1;
    rd03(buf, 0);
    GBAR; mf_lo(); GBAR;
    rd47(buf, 0);
    GBAR; mf_hi(); VMW(0); __builtin_amdgcn_s_barrier();
    rd03(buf, 1);
    GBAR; mf_lo(); GBAR;
    rd47(buf, 1);
    GBAR; mf_hi(); __builtin_amdgcn_s_barrier();
  }
#undef GBAR
#undef VMW

#pragma unroll
  for (int m = 0; m < 8; ++m)
#pragma unroll
    for (int n = 0; n < 4; ++n)
#pragma unroll
      for (int rr = 0; rr < 4; ++rr) {
        int row = bm + wr * 128 + m * 16 + l4 * 4 + rr;
        int col = bn + wc * 64 + n * 16 + l15;
        size_t ix = (size_t)row * N + col;
        float v = acc[m][n][rr];
        if (EPI == 0)      ((float*)Cout)[ix] = v;
        else if (EPI == 1) ((float*)Cout)[ix] = v + R[ix];
        else               ((bf16*)Cout)[ix] = (bf16)v;
      }
}

// ---------------- 128x128 8-wave deep-pipeline GEMM (qkv, w13) ----------------
// EPI 3: fused silu -> gate bf16 (LDS-pack).
// EPI 4: qkv fused post: cols 0-1023 -> bf16 to qkv; 1024-1279 -> rope -> k_r;
//        1280-1535 -> transposed -> vT.
template <int EPI>
__global__ __launch_bounds__(512, 4) void gemm8_bt(const bf16* __restrict__ A,
                                                   const bf16* __restrict__ BT,
                                                   void* __restrict__ Cout,
                                                   const float* __restrict__ tab,
                                                   bf16* __restrict__ krout,
                                                   bf16* __restrict__ vtout,
                                                   int N, int K) {
  extern __shared__ char smem[];   // 65536
  const int t = threadIdx.x;
  const int wid = t >> 6, l = t & 63;
  const int l15 = l & 15, l4 = l >> 4;
  const int wr = wid >> 1, wc = wid & 1;
  const int rsw = (l4 ^ ((l15 >> 1) & 3)) * 16;
  const int csw = ((t & 3) ^ ((t >> 3) & 3)) * 8;

  int nwg = gridDim.x;
  int q = nwg >> 3;
  int xcd = blockIdx.x & 7, jj = blockIdx.x >> 3;
  int L = xcd * q + jj;
  const int bm = (L & 15) * 128, bn = (L >> 4) * 128;

  const int NT = K >> 6;

  auto stage = [&](const bf16* __restrict__ G, int rowbase, int obase, int buf, int kc, int kt) {
    const bf16* src = G + (size_t)(rowbase + (t >> 2)) * K + kt * 64 + kc * 32 + csw;
    __builtin_amdgcn_global_load_lds(
        (const __attribute__((address_space(1))) void*)src,
        (__attribute__((address_space(3))) void*)(smem + obase + buf * 16384 + kc * 8192 +
                                                  wid * 1024),
        16, 0, 0);
  };
  auto ldA = [&](int buf, int kc, int m) -> bf16x8 {
    return *(const bf16x8*)(smem + buf * 16384 + kc * 8192 +
                            (wr * 32 + m * 16 + l15) * 64 + rsw);
  };
  auto ldB = [&](int buf, int kc, int n) -> bf16x8 {
    return *(const bf16x8*)(smem + 32768 + buf * 16384 + kc * 8192 +
                            (wc * 64 + n * 16 + l15) * 64 + rsw);
  };

  f32x4 acc[2][4] = {};
  bf16x8 af[2], bq[4];

  auto rdph = [&](int buf, int kc) {
#pragma unroll
    for (int m = 0; m < 2; ++m) af[m] = ldA(buf, kc, m);
#pragma unroll
    for (int n = 0; n < 4; ++n) bq[n] = ldB(buf, kc, n);
  };
  auto mf = [&]() {
    __builtin_amdgcn_s_setprio(1);
#pragma unroll
    for (int m = 0; m < 2; ++m)
#pragma unroll
      for (int n = 0; n < 4; ++n)
        acc[m][n] = __builtin_amdgcn_mfma_f32_16x16x32_bf16(af[m], bq[n], acc[m][n], 0, 0, 0);
    __builtin_amdgcn_s_setprio(0);
    __builtin_amdgcn_sched_barrier(0);
  };
#define SCB __builtin_amdgcn_sched_barrier(0)
#define VMW4 { asm volatile("s_waitcnt vmcnt(4)" ::: "memory"); SCB; }
#define VMW2 { asm volatile("s_waitcnt vmcnt(2)" ::: "memory"); SCB; }
#define VMW0 { asm volatile("s_waitcnt vmcnt(0)" ::: "memory"); SCB; }
#define SBAR { __builtin_amdgcn_s_barrier(); SCB; }

  stage(A, bm, 0, 0, 0, 0);  stage(BT, bn, 32768, 0, 0, 0);
  stage(A, bm, 0, 0, 1, 0);  stage(BT, bn, 32768, 0, 1, 0);
  stage(A, bm, 0, 1, 0, 1);  stage(BT, bn, 32768, 1, 0, 1);
  VMW4; __builtin_amdgcn_s_barrier();

  for (int kt = 0; kt < NT - 2; ++kt) {
    const int buf = kt & 1, nbuf = buf ^ 1;
    rdph(buf, 0);
    stage(A, bm, 0, nbuf, 1, kt + 1);
    stage(BT, bn, 32768, nbuf, 1, kt + 1);
    SCB; mf(); VMW4; SBAR;
    rdph(buf, 1);
    stage(A, bm, 0, buf, 0, kt + 2);
    stage(BT, bn, 32768, buf, 0, kt + 2);
    SCB; mf(); VMW4; SBAR;
  }
  {
    const int buf = (NT - 2) & 1, nbuf = buf ^ 1;
    rdph(buf, 0);
    stage(A, bm, 0, nbuf, 1, NT - 1);
    stage(BT, bn, 32768, nbuf, 1, NT - 1);
    SCB; mf(); VMW4; SBAR;
    rdph(buf, 1);
    SCB; mf(); VMW2; SBAR;
  }
  {
    const int buf = (NT - 1) & 1;
    rdph(buf, 0);
    SCB; mf(); VMW0; SBAR;
    rdph(buf, 1);
    SCB; mf();
  }
#undef SCB
#undef VMW4
#undef VMW2
#undef VMW0
#undef SBAR

  __builtin_amdgcn_s_barrier();   // all waves done with LDS slabs -> safe to alias

  if (EPI == 3) {
    bf16* wb = (bf16*)(smem + wid * 2304);     // 16 x 40 bf16
    bf16* G = (bf16*)Cout;
    const int Nc = N >> 1;
#pragma unroll
    for (int m = 0; m < 2; ++m) {
#pragma unroll
      for (int n = 0; n < 4; ++n)
#pragma unroll
        for (int rr = 0; rr < 4; ++rr) {
          float v = acc[m][n][rr];
          float part = __shfl_xor(v, 1, 64);
          if (!(l15 & 1)) {
            float s = v / (1.0f + __expf(-v));
            wb[(l4 * 4 + rr) * 40 + n * 8 + (l15 >> 1)] = (bf16)(s * part);
          }
        }
      LGKM0;
      int ROW = l >> 2, CB = l & 3;
      bf16x8 g = *(const bf16x8*)&wb[ROW * 40 + CB * 8];
      LGKM0;
      int row = bm + wr * 32 + m * 16 + ROW;
      int col = (bn >> 1) + wc * 32 + CB * 8;
      *(bf16x8*)&G[(size_t)row * Nc + col] = g;
    }
  } else {   // EPI == 4
    const int cb = bn >> 7;    // 0..11
    if (cb >= 10) {
      bf16* wbT = (bf16*)(smem + wid * 4352);
#pragma unroll
      for (int m = 0; m < 2; ++m)
#pragma unroll
        for (int n = 0; n < 4; ++n)
#pragma unroll
          for (int rr = 0; rr < 4; ++rr)
            wbT[(n * 16 + l15) * 34 + m * 16 + l4 * 4 + rr] = (bf16)acc[m][n][rr];
      LGKM0;
      bf16x8 v0 = *(const bf16x8*)&wbT[l * 34];
      bf16x8 v1 = *(const bf16x8*)&wbT[l * 34 + 8];
      bf16x8 v2 = *(const bf16x8*)&wbT[l * 34 + 16];
      bf16x8 v3 = *(const bf16x8*)&wbT[l * 34 + 24];
      LGKM0;
      int hh = ((bn - 1280) >> 6) + wc;
      int b = bm >> 10;
      int scol = (bm & 1023) + wr * 32;
      bf16* dst = &vtout[((size_t)((b * HK_ + hh) * 64 + l)) * S_ + scol];
      *(bf16x8*)&dst[0]  = v0;  *(bf16x8*)&dst[8]  = v1;
      *(bf16x8*)&dst[16] = v2;  *(bf16x8*)&dst[24] = v3;
    } else {
      bf16* wb = (bf16*)(smem + wid * 2304);
#pragma unroll
      for (int m = 0; m < 2; ++m) {
#pragma unroll
        for (int n = 0; n < 4; ++n)
#pragma unroll
          for (int rr = 0; rr < 4; ++rr)
            wb[(l4 * 4 + rr) * 72 + n * 16 + l15] = (bf16)acc[m][n][rr];
        LGKM0;
        int ROW = l >> 2, CB = l & 3;
        bf16x8 g0 = *(const bf16x8*)&wb[ROW * 72 + CB * 16];
        bf16x8 g1 = *(const bf16x8*)&wb[ROW * 72 + CB * 16 + 8];
        LGKM0;
        int row = bm + wr * 32 + m * 16 + ROW;
        if (cb < 8) {
          bf16* Cb = (bf16*)Cout;
          int col = bn + wc * 64 + CB * 16;
          *(bf16x8*)&Cb[(size_t)row * N + col] = g0;
          *(bf16x8*)&Cb[(size_t)row * N + col + 8] = g1;
        } else {
          int b = row >> 10, ss = row & 1023;
          int hh = ((bn - 1024) >> 6) + wc;
          int d0 = CB * 16;
          f32x4 t0 = *(const f32x4*)&tab[(ss * 32 + (d0 >> 1)) * 2];
          f32x4 t1 = *(const f32x4*)&tab[(ss * 32 + (d0 >> 1)) * 2 + 4];
          f32x4 t2 = *(const f32x4*)&tab[(ss * 32 + (d0 >> 1) + 4) * 2];
          f32x4 t3 = *(const f32x4*)&tab[(ss * 32 + (d0 >> 1) + 4) * 2 + 4];
          bf16x8 r0, r1;
#pragma unroll
          for (int j = 0; j < 4; ++j) {
            float a = (float)g0[2 * j], bv = (float)g0[2 * j + 1];
            float c  = (j < 2 ? t0 : t1)[(j & 1) * 2];
            float sn = (j < 2 ? t0 : t1)[(j & 1) * 2 + 1];
            r0[2 * j]     = (bf16)(a * c - bv * sn);
            r0[2 * j + 1] = (bf16)(a * sn + bv * c);
            float a2 = (float)g1[2 * j], bv2 = (float)g1[2 * j + 1];
            float c2  = (j < 2 ? t2 : t3)[(j & 1) * 2];
            float sn2 = (j < 2 ? t2 : t3)[(j & 1) * 2 + 1];
            r1[2 * j]     = (bf16)(a2 * c2 - bv2 * sn2);
            r1[2 * j + 1] = (bf16)(a2 * sn2 + bv2 * c2);
          }
          bf16* dst = &krout[((size_t)((b * HK_ + hh) * S_ + ss)) * 64 + d0];
          *(bf16x8*)&dst[0] = r0;
          *(bf16x8*)&dst[8] = r1;
        }
      }
    }
  }
}

// ---------------- flash attention (causal, GQA), KVBLK=128, in-register rope-Q ----------------
// + deferred l_run reduction
__global__ __launch_bounds__(256) void attn_k(const bf16* __restrict__ qkv,
                                              const float* __restrict__ tab,
                                              const bf16* __restrict__ k_r,
                                              const bf16* __restrict__ vT,
                                              bf16* __restrict__ o) {
  __shared__ bf16 k_lds[128 * 64];
  __shared__ bf16 v_lds[64 * 128];
  __shared__ bf16 p_lds[4][16 * 136];
  int t = threadIdx.x, w = t >> 6, l = t & 63, l15 = l & 15, l4 = l >> 4;
  int bx = blockIdx.x;
  int qt = bx & 15;
  if (bx >= 256) qt = 15 - qt;
  int head = (bx >> 4) & 15, b = bx >> 8;
  int kvh = head >> 2;
  const bf16* kh = k_r + ((size_t)(b * HK_ + kvh)) * S_ * 64;
  const bf16* vh = vT + ((size_t)(b * HK_ + kvh)) * 64 * S_;
  int q0 = qt * 64 + w * 16;
  const int ntile = (qt + 2) >> 1;

  bf16x8 aq[2];
  {
    int s = q0 + l15;
#pragma unroll
    for (int kc = 0; kc < 2; ++kc) {
      bf16x8 raw = *(const bf16x8*)&qkv[(size_t)(b * S_ + s) * 1536 + head * 64 +
                                        kc * 32 + l4 * 8];
      int d0 = kc * 16 + l4 * 4;
      f32x4 tc0 = *(const f32x4*)&tab[(s * 32 + d0) * 2];
      f32x4 tc1 = *(const f32x4*)&tab[(s * 32 + d0) * 2 + 4];
      bf16x8 out;
#pragma unroll
      for (int j = 0; j < 4; ++j) {
        float a = (float)raw[2 * j], bb = (float)raw[2 * j + 1];
        float c  = (j < 2 ? tc0 : tc1)[(j & 1) * 2];
        float sn = (j < 2 ? tc0 : tc1)[(j & 1) * 2 + 1];
        out[2 * j]     = (bf16)((a * c - bb * sn) * 0.125f);
        out[2 * j + 1] = (bf16)((a * sn + bb * c) * 0.125f);
      }
      aq[kc] = out;
    }
  }

  f32x4 acc_o[4] = {};
  float m_run[4], l_run[4];
#pragma unroll
  for (int r = 0; r < 4; ++r) { m_run[r] = -1e30f; l_run[r] = 0.f; }

  bf16x8 gk[4], gv[4];
#pragma unroll
  for (int i = 0; i < 4; ++i) {
    int c = i * 256 + t;
    gk[i] = *(const bf16x8*)&kh[(size_t)(c >> 3) * 64 + (c & 7) * 8];
    gv[i] = *(const bf16x8*)&vh[(size_t)(c >> 4) * S_ + (c & 15) * 8];
  }

  for (int j = 0; j < ntile; ++j) {
#pragma unroll
    for (int i = 0; i < 4; ++i) {
      int c = i * 256 + t;
      int krow = c >> 3, kch = (c & 7) ^ (krow & 7);
      *(bf16x8*)&k_lds[krow * 64 + kch * 8] = gk[i];
      int vrow = c >> 4, vch = (c & 15) ^ (vrow & 15);
      *(bf16x8*)&v_lds[vrow * 128 + vch * 8] = gv[i];
    }
    __syncthreads();

    bf16x8 gkn[4], gvn[4];
    if (j + 1 < ntile) {
#pragma unroll
      for (int i = 0; i < 4; ++i) {
        int c = i * 256 + t;
        gkn[i] = *(const bf16x8*)&kh[(size_t)((j + 1) * 128 + (c >> 3)) * 64 + (c & 7) * 8];
        gvn[i] = *(const bf16x8*)&vh[(size_t)(c >> 4) * S_ + (j + 1) * 128 + (c & 15) * 8];
      }
    }

    f32x4 sc[8];
#pragma unroll
    for (int nt = 0; nt < 8; ++nt) {
      f32x4 a = {};
#pragma unroll
      for (int kc = 0; kc < 2; ++kc) {
        bf16x8 bk = *(const bf16x8*)&k_lds[(nt * 16 + l15) * 64 +
                                           (((kc * 4 + l4) ^ (l15 & 7)) * 8)];
        a = __builtin_amdgcn_mfma_f32_16x16x32_bf16(aq[kc], bk, a, 0, 0, 0);
      }
      sc[nt] = a;
    }

    bool lastt = (j == ntile - 1);
#pragma unroll
    for (int r = 0; r < 4; ++r) {
      float pmax = -1e30f;
#pragma unroll
      for (int nt = 0; nt < 8; ++nt) {
        float s = sc[nt][r];
        if (lastt) {
          int kj = j * 128 + nt * 16 + l15;
          int qi = q0 + l4 * 4 + r;
          if (kj > qi) s = -1e30f;
        }
        sc[nt][r] = s;
        pmax = fmaxf(pmax, s);
      }
      if (!__all(pmax <= m_run[r] + 8.0f)) {
        float mx = pmax;
        mx = fmaxf(mx, __shfl_xor(mx, 1, 64));
        mx = fmaxf(mx, __shfl_xor(mx, 2, 64));
        mx = fmaxf(mx, __shfl_xor(mx, 4, 64));
        mx = fmaxf(mx, __shfl_xor(mx, 8, 64));
        float mn = fmaxf(m_run[r], mx);
        float scale = __expf(m_run[r] - mn);
        m_run[r] = mn;
        l_run[r] *= scale;
#pragma unroll
        for (int nt = 0; nt < 4; ++nt) acc_o[nt][r] *= scale;
      }
      float rs = 0.f;
#pragma unroll
      for (int nt = 0; nt < 8; ++nt) {
        float p = __expf(sc[nt][r] - m_run[r]);
        sc[nt][r] = p;
        rs += p;
      }
      l_run[r] += rs;
    }

#pragma unroll
    for (int nt = 0; nt < 8; ++nt)
#pragma unroll
      for (int r = 0; r < 4; ++r)
        p_lds[w][(l4 * 4 + r) * 136 + nt * 16 + l15] = (bf16)sc[nt][r];
    LGKM0;

#pragma unroll
    for (int kc = 0; kc < 4; ++kc) {
      bf16x8 pf = *(const bf16x8*)&p_lds[w][l15 * 136 + kc * 32 + l4 * 8];
#pragma unroll
      for (int nt = 0; nt < 4; ++nt) {
        bf16x8 vf = *(const bf16x8*)&v_lds[(nt * 16 + l15) * 128 +
                                           (((kc * 4 + l4) ^ l15) * 8)];
        acc_o[nt] = __builtin_amdgcn_mfma_f32_16x16x32_bf16(pf, vf, acc_o[nt], 0, 0, 0);
      }
    }
    __syncthreads();

#pragma unroll
    for (int i = 0; i < 4; ++i) { gk[i] = gkn[i]; gv[i] = gvn[i]; }
  }

#pragma unroll
  for (int r = 0; r < 4; ++r) {
    float lr = l_run[r];
    lr += __shfl_xor(lr, 1, 64);
    lr += __shfl_xor(lr, 2, 64);
    lr += __shfl_xor(lr, 4, 64);
    lr += __shfl_xor(lr, 8, 64);
    l_run[r] = lr;
  }

#pragma unroll
  for (int nt = 0; nt < 4; ++nt)
#pragma unroll
    for (int r = 0; r < 4; ++r) {
      float ov = acc_o[nt][r] / l_run[r];
      int s = qt * 64 + w * 16 + l4 * 4 + r;
      o[((size_t)(b * S_ + s)) * D_ + head * 64 + nt * 16 + l15] = (bf16)ov;
    }
}

// =======================================================================
extern "C" void kernel_launch(void* const* d_in, const int* in_sizes, int n_in,
                              void* d_out, int out_size, void* d_ws, size_t ws_size,
                              hipStream_t stream) {
  const int* tokens  = (const int*)d_in[0];
  const float* tok_emb = (const float*)d_in[2];
  const float* wq = (const float*)d_in[3];
  const float* wk = (const float*)d_in[4];
  const float* wv = (const float*)d_in[5];
  const float* wo = (const float*)d_in[6];
  const float* w1 = (const float*)d_in[7];
  const float* w2 = (const float*)d_in[8];
  const float* w3 = (const float*)d_in[9];
  const float* anw = (const float*)d_in[10];
  const float* fnw = (const float*)d_in[11];
  const float* finw = (const float*)d_in[12];
  const float* outw = (const float*)d_in[13];

  (void)hipFuncSetAttribute((const void*)gemm256_bt<0>,
                            hipFuncAttributeMaxDynamicSharedMemorySize, 131072);
  (void)hipFuncSetAttribute((const void*)gemm8_bt<3>,
                            hipFuncAttributeMaxDynamicSharedMemorySize, 65536);
  (void)hipFuncSetAttribute((const void*)gemm8_bt<4>,
                            hipFuncAttributeMaxDynamicSharedMemorySize, 65536);

  auto al = [](size_t x) { return (x + 255) & ~(size_t)255; };
  const size_t WTB   = 11272192ull * 2;
  const size_t OUTWTB = (size_t)V_ * D_ * 2;
  const size_t HB   = (size_t)B_ * S_ * D_ * 4;
  const size_t XBB  = (size_t)B_ * S_ * D_ * 2;
  const size_t QKVB = (size_t)B_ * S_ * 1536 * 2;
  const size_t KRB  = (size_t)B_ * HK_ * S_ * 64 * 2;
  const size_t OB   = (size_t)B_ * S_ * D_ * 2;
  const size_t GATEB = (size_t)B_ * S_ * 2816 * 2;
  const size_t TABB = (size_t)S_ * 32 * 2 * 4;
  const size_t PARTB = (size_t)B_ * S_ * D_ * 4 * 2;

  size_t fixed = al(OUTWTB) + al(HB) + al(XBB) + al(QKVB) + al(KRB) + al(KRB) +
                 al(OB) + al(GATEB) + al(TABB) + al(PARTB);
  bool allup = ws_size >= fixed + 8 * al(WTB) + 4096;
  int nslots = allup ? 8 : 1;

  char* p = (char*)d_ws;
  bf16* wT    = (bf16*)p; p += (size_t)nslots * al(WTB);
  bf16* outwT = (bf16*)p; p += al(OUTWTB);
  float* h    = (float*)p; p += al(HB);
  bf16* xb    = (bf16*)p; p += al(XBB);
  bf16* qkv   = (bf16*)p; p += al(QKVB);
  bf16* k_r   = (bf16*)p; p += al(KRB);
  bf16* vTb   = (bf16*)p; p += al(KRB);
  bf16* ob    = (bf16*)p; p += al(OB);
  bf16* gate  = (bf16*)p; p += al(GATEB);
  float* tab  = (float*)p; p += al(TABB);
  float* part = (float*)p; p += al(PARTB);

  const size_t WTS = al(WTB) / 2;

  auto tr = [&](const float* src, size_t srcStride, bf16* dst, size_t dstStride,
                int Kd, int Nd, int layers, int rowMul, int rowAdd) {
    transpose_cvt<<<dim3(Nd / 64, Kd / 64, layers), 256, 0, stream>>>(
        src, dst, Kd, Nd, (long long)srcStride, (long long)dstStride, rowMul, rowAdd);
  };

  if (allup) {
    // single mega-dispatch: rope table + embed/rms + all weight transposes
    setup_k<<<32192, 256, 0, stream>>>(tokens, tok_emb, anw, h, xb, tab,
                                       outw, outwT, wq, wk, wv, wo, w1, w3, w2,
                                       wT, (long long)WTS);
  } else {
    ropetab_k<<<128, 256, 0, stream>>>(tab);
    embedrms_k<<<B_ * S_, 256, 0, stream>>>(tokens, tok_emb, anw, h, xb);
    tr(outw, 0, outwT, 0, 1024, 32000, 1, 1, 0);
  }

  for (int l = 0; l < L_; ++l) {
    bf16* wtl = wT + (allup ? (size_t)l * WTS : 0);
    if (!allup) {
      tr(wq + (size_t)l * 1024 * 1024, 0, wtl + OFFD_QKV, 0, 1024, 1024, 1, 1, 0);
      tr(wk + (size_t)l * 1024 * 256,  0, wtl + OFFD_WK,  0, 1024, 256, 1, 1, 0);
      tr(wv + (size_t)l * 1024 * 256,  0, wtl + OFFD_WV,  0, 1024, 256, 1, 1, 0);
      tr(wo + (size_t)l * 1024 * 1024, 0, wtl + OFFD_WO,  0, 1024, 1024, 1, 1, 0);
      tr(w1 + (size_t)l * 1024 * 2816, 0, wtl + OFFD_W13, 0, 1024, 2816, 1, 2, 0);
      tr(w3 + (size_t)l * 1024 * 2816, 0, wtl + OFFD_W13, 0, 1024, 2816, 1, 2, 1);
      tr(w2 + (size_t)l * 2816 * 1024, 0, wtl + OFFD_W2,  0, 2816, 1024, 1, 1, 0);
    }

    gemm8_bt<4><<<192, 512, 65536, stream>>>(xb, wtl + OFFD_QKV, qkv, tab, k_r, vTb,
                                             1536, 1024);
    attn_k<<<B_ * HQ_ * (S_ / 64), 256, 0, stream>>>(qkv, tab, k_r, vTb, ob);
    gemm_bt<1, 32><<<dim3(64, 8, 1), 256, 0, stream>>>(ob, wtl + OFFD_WO, h, h,
                                                       2048, 1024, 1024, 1024, 1024, 0, 0);
    rmsnorm_k<<<B_ * S_, 256, 0, stream>>>(h, fnw + l * D_, xb);
    gemm8_bt<3><<<704, 512, 65536, stream>>>(xb, wtl + OFFD_W13, gate, nullptr, nullptr,
                                             nullptr, 5632, 1024);
    gemm_bt<0, 64><<<dim3(32, 8, 2), 256, 0, stream>>>(gate, wtl + OFFD_W2, part, nullptr,
                                                       2048, 1024, 1408, 2816, 2816,
                                                       1408, 2097152ll);
    redrms_k<<<B_ * S_, 256, 0, stream>>>(part, h,
                                          (l < L_ - 1) ? (anw + (l + 1) * D_) : finw, xb);
  }

  gemm256_bt<0><<<1000, 512, 131072, stream>>>(xb, outwT, d_out, nullptr, 32000, 1024);
}